// Round 6
// baseline (260.726 us; speedup 1.0000x reference)
//
#include <hip/hip_runtime.h>
#include <cmath>

#define NB 32
#define NS 256
#define NT 64
#define START_TAG 62
#define STOP_TAG 63
#define CL 8                 // matrices per chunk
#define NCH 32               // chunks per batch
#define GS 8.0f              // M = exp(f - GS)
#define LOG64 4.1588830833596715f
#define CMAT_SHORTS ((size_t)NB * NCH * NT * NT)

typedef __attribute__((ext_vector_type(8))) short short8;
typedef __attribute__((ext_vector_type(4))) float float4v;

union FragU { unsigned u[4]; short8 s; unsigned short h[8]; };

__device__ inline unsigned pkbf(float a, float b) {
  unsigned ua = (__float_as_uint(a) + 0x8000u) >> 16;
  unsigned ub = (__float_as_uint(b) + 0x8000u) & 0xffff0000u;
  return ua | ub;
}

// Fused: wave-per-chunk product (zero block barriers) + last-wave-per-batch
// combine, single launch. Completion via device-scope atomics + __threadfence.
__global__ __launch_bounds__(256) void crf_fused(
    const float* __restrict__ feat, const int* __restrict__ targets,
    const int* __restrict__ lengths, unsigned short* __restrict__ cmat,
    unsigned int* __restrict__ cnt, float* __restrict__ out) {
  const int wv  = threadIdx.x >> 6;
  const int gid = blockIdx.x * 4 + wv;        // 0..1023
  const int b   = gid >> 5;                   // NCH = 32
  const int c   = gid & 31;
  const int len = lengths[b];
  const int t1  = 1 + c * CL;
  const int nmat = min(len, t1 + CL) - t1;

  const int lane = threadIdx.x & 63;
  const int q  = lane >> 4;
  const int cc = lane & 15;

  __shared__ float sv[NT];   // used only by the (single) combining wave

  // ================= Phase A: chunk product (R5-proven) =================
  if (nmat > 0) {
    const float* fb = feat + ((size_t)b * NS + t1) * (NT * NT);

    FragU BQ[2][4];
    #pragma unroll
    for (int h = 0; h < 2; ++h)
      #pragma unroll
      for (int tj = 0; tj < 4; ++tj) {
        const float* p = fb + (16 * tj + cc) * NT + 32 * h + 8 * q;
        float4 x = *(const float4*)p;
        float4 y = *(const float4*)(p + 4);
        BQ[h][tj].u[0] = pkbf(__expf(x.x - GS), __expf(x.y - GS));
        BQ[h][tj].u[1] = pkbf(__expf(x.z - GS), __expf(x.w - GS));
        BQ[h][tj].u[2] = pkbf(__expf(y.x - GS), __expf(y.y - GS));
        BQ[h][tj].u[3] = pkbf(__expf(y.z - GS), __expf(y.w - GS));
      }

    float raw[4][2][8];
    if (nmat > 1) {
      const float* p = fb + NT * NT;
      #pragma unroll
      for (int mi = 0; mi < 4; ++mi)
        #pragma unroll
        for (int kh = 0; kh < 2; ++kh)
          #pragma unroll
          for (int j = 0; j < 8; ++j)
            raw[mi][kh][j] = p[(32 * kh + 8 * q + j) * NT + 16 * mi + cc];
    }

    const int src0 = (((q & 1) * 2) << 4) | cc;
    const int src1 = src0 + 16;
    const bool hi = (q >> 1) != 0;

    for (int k = 1; k < nmat; ++k) {
      FragU FA[4][2];
      #pragma unroll
      for (int mi = 0; mi < 4; ++mi)
        #pragma unroll
        for (int kh = 0; kh < 2; ++kh)
          #pragma unroll
          for (int j2 = 0; j2 < 4; ++j2)
            FA[mi][kh].u[j2] =
                pkbf(__expf(raw[mi][kh][2 * j2]     - (GS + LOG64)),
                     __expf(raw[mi][kh][2 * j2 + 1] - (GS + LOG64)));

      if (k + 1 < nmat) {
        const float* p = fb + (size_t)(k + 1) * (NT * NT);
        #pragma unroll
        for (int mi = 0; mi < 4; ++mi)
          #pragma unroll
          for (int kh = 0; kh < 2; ++kh)
            #pragma unroll
            for (int j = 0; j < 8; ++j)
              raw[mi][kh][j] = p[(32 * kh + 8 * q + j) * NT + 16 * mi + cc];
      }

      float4v acc[4][4];
      #pragma unroll
      for (int ti = 0; ti < 4; ++ti)
        #pragma unroll
        for (int tj = 0; tj < 4; ++tj) {
          float4v z = {0.f, 0.f, 0.f, 0.f};
          z = __builtin_amdgcn_mfma_f32_16x16x32_bf16(FA[ti][0].s, BQ[0][tj].s, z, 0, 0, 0);
          acc[ti][tj] = __builtin_amdgcn_mfma_f32_16x16x32_bf16(FA[ti][1].s, BQ[1][tj].s, z, 0, 0, 0);
        }

      unsigned pk01[4][4], pk23[4][4];
      #pragma unroll
      for (int ti = 0; ti < 4; ++ti)
        #pragma unroll
        for (int tj = 0; tj < 4; ++tj) {
          pk01[ti][tj] = pkbf(acc[ti][tj][0], acc[ti][tj][1]);
          pk23[ti][tj] = pkbf(acc[ti][tj][2], acc[ti][tj][3]);
        }

      #pragma unroll
      for (int h = 0; h < 2; ++h)
        #pragma unroll
        for (int tj = 0; tj < 4; ++tj) {
          unsigned a0 = (unsigned)__shfl((int)pk01[2 * h][tj],     src0);
          unsigned b0 = (unsigned)__shfl((int)pk01[2 * h + 1][tj], src0);
          unsigned a1 = (unsigned)__shfl((int)pk23[2 * h][tj],     src0);
          unsigned b1 = (unsigned)__shfl((int)pk23[2 * h + 1][tj], src0);
          unsigned a2 = (unsigned)__shfl((int)pk01[2 * h][tj],     src1);
          unsigned b2 = (unsigned)__shfl((int)pk01[2 * h + 1][tj], src1);
          unsigned a3 = (unsigned)__shfl((int)pk23[2 * h][tj],     src1);
          unsigned b3 = (unsigned)__shfl((int)pk23[2 * h + 1][tj], src1);
          BQ[h][tj].u[0] = hi ? b0 : a0;
          BQ[h][tj].u[1] = hi ? b1 : a1;
          BQ[h][tj].u[2] = hi ? b2 : a2;
          BQ[h][tj].u[3] = hi ? b3 : a3;
        }
    }

    unsigned short* dst = cmat + ((size_t)b * NCH + c) * (NT * NT);
    #pragma unroll
    for (int h = 0; h < 2; ++h)
      #pragma unroll
      for (int tj = 0; tj < 4; ++tj)
        #pragma unroll
        for (int j = 0; j < 8; ++j)
          dst[(32 * h + 8 * q + j) * NT + 16 * tj + cc] = BQ[h][tj].h[j];
  }

  // ================= Completion signal (device scope) =================
  __threadfence();                      // release: cmat stores visible
  unsigned old = 0;
  if (lane == 0) old = atomicAdd(&cnt[b], 1u);
  old = (unsigned)__shfl((int)old, 0);
  if (old != NCH - 1) return;           // not the last wave for this batch
  __threadfence();                      // acquire: see all 32 chunk products

  // ================= Phase B: combine for batch b (one wave) ============
  const int j = lane;
  const float* f0 = feat + (size_t)b * NS * (NT * NT);

  float gold = 0.f;
  #pragma unroll
  for (int g = 0; g < 4; ++g) {
    const int s = j + 64 * g;
    if (s < len) {
      const int tgt = targets[b * NS + s];
      gold += f0[(size_t)s * (NT * NT) + tgt];
    }
  }

  float x = f0[START_TAG * NT + j];
  float m = x;
  #pragma unroll
  for (int off = 32; off; off >>= 1) m = fmaxf(m, __shfl_xor(m, off));
  float v = __expf(x - m);
  float L = m;

  const int nch = (len - 1 + CL - 1) / CL;
  const uint4* base = (const uint4*)(cmat + (size_t)b * NCH * (NT * NT)) + j * 8;

  uint4 QA[8], QB[8], QC[8];
  auto LQ = [&](uint4* D, int c2) {
    if (c2 < nch) {
      const uint4* P = base + (size_t)c2 * 512;
      #pragma unroll
      for (int w = 0; w < 8; ++w) D[w] = P[w];
    }
  };
  auto STEP = [&](const uint4* Q, int c2) {
    sv[j] = v;
    __builtin_amdgcn_wave_barrier();
    float ac0 = 0.f, ac1 = 0.f, ac2 = 0.f, ac3 = 0.f;
    const float4* svp = (const float4*)sv;
    #pragma unroll
    for (int w = 0; w < 8; ++w) {
      uint4 qq = Q[w];
      float4 s0 = svp[2 * w], s1 = svp[2 * w + 1];
      ac0 = fmaf(__uint_as_float(qq.x << 16), s0.x, ac0);
      ac1 = fmaf(__uint_as_float(qq.x & 0xffff0000u), s0.y, ac1);
      ac2 = fmaf(__uint_as_float(qq.y << 16), s0.z, ac2);
      ac3 = fmaf(__uint_as_float(qq.y & 0xffff0000u), s0.w, ac3);
      ac0 = fmaf(__uint_as_float(qq.z << 16), s1.x, ac0);
      ac1 = fmaf(__uint_as_float(qq.z & 0xffff0000u), s1.y, ac1);
      ac2 = fmaf(__uint_as_float(qq.w << 16), s1.z, ac2);
      ac3 = fmaf(__uint_as_float(qq.w & 0xffff0000u), s1.w, ac3);
    }
    float acc = (ac0 + ac1) + (ac2 + ac3);
    __builtin_amdgcn_wave_barrier();
    const int tt1 = 1 + c2 * CL;
    const int nm = min(len, tt1 + CL) - tt1;
    L += (float)nm * GS + (float)(nm - 1) * LOG64;
    float mm = acc;
    #pragma unroll
    for (int off = 32; off; off >>= 1) mm = fmaxf(mm, __shfl_xor(mm, off));
    v = acc / mm;
    L += __logf(mm);
  };

  LQ(QA, 0); LQ(QB, 1); LQ(QC, 2);
  for (int c2 = 0; c2 < nch; c2 += 3) {
    STEP(QA, c2);
    LQ(QA, c2 + 3);
    if (c2 + 1 < nch) { STEP(QB, c2 + 1); LQ(QB, c2 + 4); }
    if (c2 + 2 < nch) { STEP(QC, c2 + 2); LQ(QC, c2 + 5); }
  }

  float lv = __logf(v);
  float path = L + __shfl(lv, STOP_TAG);

  #pragma unroll
  for (int off = 32; off; off >>= 1) gold += __shfl_down(gold, off);
  if (j == 0) atomicAdd(out, (path - gold) * (1.0f / (float)NB));
}

extern "C" void kernel_launch(void* const* d_in, const int* in_sizes, int n_in,
                              void* d_out, int out_size, void* d_ws, size_t ws_size,
                              hipStream_t stream) {
  const float* feat    = (const float*)d_in[0];
  const int*   targets = (const int*)d_in[1];
  const int*   lengths = (const int*)d_in[2];
  unsigned short* cmat = (unsigned short*)d_ws;             // 8 MB bf16 products
  unsigned int* cnt = (unsigned int*)((char*)d_ws + CMAT_SHORTS * 2);
  float* out = (float*)d_out;

  hipMemsetAsync(cnt, 0, NB * sizeof(unsigned int), stream);
  hipMemsetAsync(d_out, 0, sizeof(float), stream);
  crf_fused<<<NB * NCH / 4, 256, 0, stream>>>(feat, targets, lengths, cmat, cnt, out);
}

// Round 7
// 213.207 us; speedup vs baseline: 1.2229x; 1.2229x over previous
//
#include <hip/hip_runtime.h>
#include <cmath>

#define NB 32
#define NS 256
#define NT 64
#define START_TAG 62
#define STOP_TAG 63
#define CL 8                 // matrices per chunk
#define NCH 32               // chunks per batch
#define GS 8.0f              // M = exp(f - GS)
#define LOG64 4.1588830833596715f

typedef __attribute__((ext_vector_type(8))) short short8;
typedef __attribute__((ext_vector_type(4))) float float4v;

union FragU { unsigned u[4]; short8 s; unsigned short h[8]; };

__device__ inline unsigned pkbf(float a, float b) {
  unsigned ua = (__float_as_uint(a) + 0x8000u) >> 16;
  unsigned ub = (__float_as_uint(b) + 0x8000u) & 0xffff0000u;
  return ua | ub;
}

// ---------------- Phase 1: wave-per-chunk matrix product, ZERO barriers -----
// (R5-proven structure: wave-private running product in B-frag registers,
//  MFMA multiply, in-wave shuffle repack, no LDS, no __syncthreads.)
__global__ __launch_bounds__(256) void chunk_kernel(
    const float* __restrict__ feat, const int* __restrict__ lengths,
    unsigned short* __restrict__ cmat, float* __restrict__ out) {
  if (blockIdx.x == 0 && threadIdx.x == 0) out[0] = 0.f;  // replaces memset launch

  const int wv  = threadIdx.x >> 6;
  const int gid = blockIdx.x * 4 + wv;        // 0..1023
  const int b   = gid >> 5;                   // NCH = 32
  const int c   = gid & 31;
  const int len = lengths[b];
  const int t1  = 1 + c * CL;
  const int nmat = min(len, t1 + CL) - t1;
  if (nmat <= 0) return;

  const int lane = threadIdx.x & 63;
  const int q  = lane >> 4;
  const int cc = lane & 15;

  const float* fb = feat + ((size_t)b * NS + t1) * (NT * NT);

  // BQ = E0^T in B-frag layout: BQ[h][tj] elem j = exp(fb[16tj+cc][32h+8q+j]-GS)
  FragU BQ[2][4];
  #pragma unroll
  for (int h = 0; h < 2; ++h)
    #pragma unroll
    for (int tj = 0; tj < 4; ++tj) {
      const float* p = fb + (16 * tj + cc) * NT + 32 * h + 8 * q;
      float4 x = *(const float4*)p;
      float4 y = *(const float4*)(p + 4);
      BQ[h][tj].u[0] = pkbf(__expf(x.x - GS), __expf(x.y - GS));
      BQ[h][tj].u[1] = pkbf(__expf(x.z - GS), __expf(x.w - GS));
      BQ[h][tj].u[2] = pkbf(__expf(y.x - GS), __expf(y.y - GS));
      BQ[h][tj].u[3] = pkbf(__expf(y.z - GS), __expf(y.w - GS));
    }

  // prefetch matrix t1+1 in A^T pattern: raw[mi][kh][j] = f[32kh+8q+j][16mi+cc]
  float raw[4][2][8];
  if (nmat > 1) {
    const float* p = fb + NT * NT;
    #pragma unroll
    for (int mi = 0; mi < 4; ++mi)
      #pragma unroll
      for (int kh = 0; kh < 2; ++kh)
        #pragma unroll
        for (int j = 0; j < 8; ++j)
          raw[mi][kh][j] = p[(32 * kh + 8 * q + j) * NT + 16 * mi + cc];
  }

  const int src0 = (((q & 1) * 2) << 4) | cc;
  const int src1 = src0 + 16;
  const bool hi = (q >> 1) != 0;

  for (int k = 1; k < nmat; ++k) {
    FragU FA[4][2];
    #pragma unroll
    for (int mi = 0; mi < 4; ++mi)
      #pragma unroll
      for (int kh = 0; kh < 2; ++kh)
        #pragma unroll
        for (int j2 = 0; j2 < 4; ++j2)
          FA[mi][kh].u[j2] =
              pkbf(__expf(raw[mi][kh][2 * j2]     - (GS + LOG64)),
                   __expf(raw[mi][kh][2 * j2 + 1] - (GS + LOG64)));

    if (k + 1 < nmat) {
      const float* p = fb + (size_t)(k + 1) * (NT * NT);
      #pragma unroll
      for (int mi = 0; mi < 4; ++mi)
        #pragma unroll
        for (int kh = 0; kh < 2; ++kh)
          #pragma unroll
          for (int j = 0; j < 8; ++j)
            raw[mi][kh][j] = p[(32 * kh + 8 * q + j) * NT + 16 * mi + cc];
    }

    float4v acc[4][4];
    #pragma unroll
    for (int ti = 0; ti < 4; ++ti)
      #pragma unroll
      for (int tj = 0; tj < 4; ++tj) {
        float4v z = {0.f, 0.f, 0.f, 0.f};
        z = __builtin_amdgcn_mfma_f32_16x16x32_bf16(FA[ti][0].s, BQ[0][tj].s, z, 0, 0, 0);
        acc[ti][tj] = __builtin_amdgcn_mfma_f32_16x16x32_bf16(FA[ti][1].s, BQ[1][tj].s, z, 0, 0, 0);
      }

    unsigned pk01[4][4], pk23[4][4];
    #pragma unroll
    for (int ti = 0; ti < 4; ++ti)
      #pragma unroll
      for (int tj = 0; tj < 4; ++tj) {
        pk01[ti][tj] = pkbf(acc[ti][tj][0], acc[ti][tj][1]);
        pk23[ti][tj] = pkbf(acc[ti][tj][2], acc[ti][tj][3]);
      }

    #pragma unroll
    for (int h = 0; h < 2; ++h)
      #pragma unroll
      for (int tj = 0; tj < 4; ++tj) {
        unsigned a0 = (unsigned)__shfl((int)pk01[2 * h][tj],     src0);
        unsigned b0 = (unsigned)__shfl((int)pk01[2 * h + 1][tj], src0);
        unsigned a1 = (unsigned)__shfl((int)pk23[2 * h][tj],     src0);
        unsigned b1 = (unsigned)__shfl((int)pk23[2 * h + 1][tj], src0);
        unsigned a2 = (unsigned)__shfl((int)pk01[2 * h][tj],     src1);
        unsigned b2 = (unsigned)__shfl((int)pk01[2 * h + 1][tj], src1);
        unsigned a3 = (unsigned)__shfl((int)pk23[2 * h][tj],     src1);
        unsigned b3 = (unsigned)__shfl((int)pk23[2 * h + 1][tj], src1);
        BQ[h][tj].u[0] = hi ? b0 : a0;
        BQ[h][tj].u[1] = hi ? b1 : a1;
        BQ[h][tj].u[2] = hi ? b2 : a2;
        BQ[h][tj].u[3] = hi ? b3 : a3;
      }
  }

  unsigned short* dst = cmat + ((size_t)b * NCH + c) * (NT * NT);
  #pragma unroll
  for (int h = 0; h < 2; ++h)
    #pragma unroll
    for (int tj = 0; tj < 4; ++tj)
      #pragma unroll
      for (int j = 0; j < 8; ++j)
        dst[(32 * h + 8 * q + j) * NT + 16 * tj + cc] = BQ[h][tj].h[j];
}

// ---------------- Phase 2: sequential combine + gold + finalize -------------
// R6-proven combine body (depth-3 prefetch ring), standalone launch.
__global__ __launch_bounds__(64) void combine_kernel(
    const float* __restrict__ feat, const int* __restrict__ targets,
    const int* __restrict__ lengths, const unsigned int* __restrict__ cmat,
    float* __restrict__ out) {
  const int b = blockIdx.x;
  const int j = threadIdx.x;
  __shared__ float sv[NT];
  const int len = lengths[b];
  const float* f0 = feat + (size_t)b * NS * (NT * NT);

  float gold = 0.f;
  #pragma unroll
  for (int g = 0; g < 4; ++g) {
    const int s = j + 64 * g;
    if (s < len) {
      const int tgt = targets[b * NS + s];
      gold += f0[(size_t)s * (NT * NT) + tgt];
    }
  }

  float x = f0[START_TAG * NT + j];
  float m = x;
  #pragma unroll
  for (int off = 32; off; off >>= 1) m = fmaxf(m, __shfl_xor(m, off));
  float v = __expf(x - m);
  float L = m;

  const int nch = (len - 1 + CL - 1) / CL;
  const uint4* base = (const uint4*)cmat + (size_t)b * NCH * 512 + j * 8;

  uint4 QA[8], QB[8], QC[8];
  auto LQ = [&](uint4* D, int c2) {
    if (c2 < nch) {
      const uint4* P = base + (size_t)c2 * 512;
      #pragma unroll
      for (int w = 0; w < 8; ++w) D[w] = P[w];
    }
  };
  auto STEP = [&](const uint4* Q, int c2) {
    sv[j] = v;
    __builtin_amdgcn_wave_barrier();
    float ac0 = 0.f, ac1 = 0.f, ac2 = 0.f, ac3 = 0.f;
    const float4* svp = (const float4*)sv;
    #pragma unroll
    for (int w = 0; w < 8; ++w) {
      uint4 qq = Q[w];
      float4 s0 = svp[2 * w], s1 = svp[2 * w + 1];
      ac0 = fmaf(__uint_as_float(qq.x << 16), s0.x, ac0);
      ac1 = fmaf(__uint_as_float(qq.x & 0xffff0000u), s0.y, ac1);
      ac2 = fmaf(__uint_as_float(qq.y << 16), s0.z, ac2);
      ac3 = fmaf(__uint_as_float(qq.y & 0xffff0000u), s0.w, ac3);
      ac0 = fmaf(__uint_as_float(qq.z << 16), s1.x, ac0);
      ac1 = fmaf(__uint_as_float(qq.z & 0xffff0000u), s1.y, ac1);
      ac2 = fmaf(__uint_as_float(qq.w << 16), s1.z, ac2);
      ac3 = fmaf(__uint_as_float(qq.w & 0xffff0000u), s1.w, ac3);
    }
    float acc = (ac0 + ac1) + (ac2 + ac3);
    __builtin_amdgcn_wave_barrier();
    const int tt1 = 1 + c2 * CL;
    const int nm = min(len, tt1 + CL) - tt1;
    L += (float)nm * GS + (float)(nm - 1) * LOG64;
    float mm = acc;
    #pragma unroll
    for (int off = 32; off; off >>= 1) mm = fmaxf(mm, __shfl_xor(mm, off));
    v = acc / mm;
    L += __logf(mm);
  };

  LQ(QA, 0); LQ(QB, 1); LQ(QC, 2);
  for (int c2 = 0; c2 < nch; c2 += 3) {
    STEP(QA, c2);
    LQ(QA, c2 + 3);
    if (c2 + 1 < nch) { STEP(QB, c2 + 1); LQ(QB, c2 + 4); }
    if (c2 + 2 < nch) { STEP(QC, c2 + 2); LQ(QC, c2 + 5); }
  }

  float lv = __logf(v);
  float path = L + __shfl(lv, STOP_TAG);

  #pragma unroll
  for (int off = 32; off; off >>= 1) gold += __shfl_down(gold, off);
  if (j == 0) atomicAdd(out, (path - gold) * (1.0f / (float)NB));
}

extern "C" void kernel_launch(void* const* d_in, const int* in_sizes, int n_in,
                              void* d_out, int out_size, void* d_ws, size_t ws_size,
                              hipStream_t stream) {
  const float* feat    = (const float*)d_in[0];
  const int*   targets = (const int*)d_in[1];
  const int*   lengths = (const int*)d_in[2];
  unsigned short* cmat = (unsigned short*)d_ws;   // 8 MB bf16 chunk products
  float* out = (float*)d_out;

  chunk_kernel<<<NB * NCH / 4, 256, 0, stream>>>(feat, lengths, cmat, out);
  combine_kernel<<<NB, 64, 0, stream>>>(feat, targets, lengths,
                                        (const unsigned int*)cmat, out);
}